// Round 10
// baseline (328.092 us; speedup 1.0000x reference)
//
#include <hip/hip_runtime.h>
#include <hip/hip_fp16.h>

#define DD 64
#define NB 256          // buckets == CSR blocks; requires n <= 65536

// ---------------------------------------------------------------------------
// Inline int64-vs-int32 detection: first 128 odd u32 words all zero <=> int64.
__device__ __forceinline__ int detect_is64(const unsigned int* p, int E,
                                           int tid, int* sflag) {
  if (tid == 0) *sflag = 1;
  __syncthreads();
  int lim = E < 128 ? E : 128;
  if (tid < lim && p[2 * tid + 1] != 0u) *sflag = 0;
  __syncthreads();
  return *sflag;
}

// Software grid barrier: all NB blocks arrive; counters pre-zeroed by memset.
__device__ __forceinline__ void gbar(int* ct, int slot, int target) {
  __syncthreads();
  if (threadIdx.x == 0) {
    __threadfence();
    __hip_atomic_fetch_add(&ct[slot], 1, __ATOMIC_RELEASE,
                           __HIP_MEMORY_SCOPE_AGENT);
    while (__hip_atomic_load(&ct[slot], __ATOMIC_ACQUIRE,
                             __HIP_MEMORY_SCOPE_AGENT) < target) {
      __builtin_amdgcn_s_sleep(2);
    }
    __threadfence();
  }
  __syncthreads();
}

// ---- single cooperative CSR build: hist -> scan -> scatter -> finalize ----
// grid = NB blocks x 256 threads (1 block/CU on MI355X -> co-residency safe).
__global__ __launch_bounds__(256) void csr_coop_kernel(
    const void* __restrict__ eidx, int E, int n, int chunk,
    int* __restrict__ histPB, int* __restrict__ localpre,
    int* __restrict__ tot, int* __restrict__ bucketBase,
    int* __restrict__ csrBase, int* __restrict__ offs,
    float* __restrict__ dinv, unsigned int* __restrict__ rec,
    int* __restrict__ col, int* __restrict__ ct) {
  int blk = blockIdx.x, tid = threadIdx.x;
  __shared__ int sflag;
  int is64 = detect_is64((const unsigned int*)eidx, E, tid, &sflag);
  __shared__ int sh[NB];
  __shared__ int sc[NB];
  __shared__ int scur[NB];

  // P1: per-block histogram of dst buckets over this block's edge slice
  sh[tid] = 0;
  __syncthreads();
  int seg = (E + NB - 1) / NB;
  int e0 = blk * seg;
  int e1 = min(e0 + seg, E);
  for (int e = e0 + tid; e < e1; e += 256) {
    int d = is64 ? (int)((const long long*)eidx)[e + E]
                 : ((const int*)eidx)[e + E];
    atomicAdd(&sh[d / chunk], 1);
  }
  __syncthreads();
  histPB[blk * NB + tid] = sh[tid];
  gbar(ct, 0, NB);

  // P2a: this block owns bucket `blk`: scan its per-source-block counts
  {
    int v = histPB[tid * NB + blk];
    sc[tid] = v;
    __syncthreads();
    for (int off = 1; off < 256; off <<= 1) {
      int t = (tid >= off) ? sc[tid - off] : 0;
      __syncthreads();
      sc[tid] += t;
      __syncthreads();
    }
    localpre[blk * NB + tid] = sc[tid] - v;
    if (tid == 255) tot[blk] = sc[255];
  }
  gbar(ct, 1, NB);

  // P2b: block 0 scans bucket totals -> bucketBase, csrBase
  if (blk == 0) {
    int v = tot[tid];
    sc[tid] = v;
    __syncthreads();
    for (int off = 1; off < 256; off <<= 1) {
      int t = (tid >= off) ? sc[tid - off] : 0;
      __syncthreads();
      sc[tid] += t;
      __syncthreads();
    }
    int excl = sc[tid] - v;
    bucketBase[tid] = excl;
    if (tid == 255) { bucketBase[NB] = excl + v; offs[n] = E + n; }
    int dpre = tid * chunk; if (dpre > n) dpre = n;
    csrBase[tid] = excl + dpre;
  }
  gbar(ct, 2, NB);

  // P3: bucketed scatter of packed records (src<<16 | local_dst)
  sh[tid] = bucketBase[tid] + localpre[tid * NB + blk];
  __syncthreads();
  for (int e = e0 + tid; e < e1; e += 256) {
    int s, d;
    if (is64) {
      const long long* p = (const long long*)eidx;
      s = (int)p[e]; d = (int)p[e + E];
    } else {
      const int* p = (const int*)eidx;
      s = p[e]; d = p[e + E];
    }
    int b = d / chunk;
    int ld = d - b * chunk;
    int pos = atomicAdd(&sh[b], 1);
    rec[pos] = ((unsigned int)s << 16) | (unsigned int)ld;
  }
  gbar(ct, 3, NB);

  // P4: per-bucket CSR finalize (offs, dinv, col)
  int d0 = blk * chunk;
  if (d0 >= n) return;
  int nd = min(chunk, n - d0);
  int jb0 = bucketBase[blk], jb1 = bucketBase[blk + 1];
  int cb = csrBase[blk];
  sh[tid] = (tid < nd) ? 1 : 0;   // self-loop seed
  __syncthreads();
  for (int j = jb0 + tid; j < jb1; j += 256)
    atomicAdd(&sh[rec[j] & 0xFFFFu], 1);
  __syncthreads();
  int deg = sh[tid];
  sc[tid] = deg;
  __syncthreads();
  for (int off = 1; off < 256; off <<= 1) {
    int t = (tid >= off) ? sc[tid - off] : 0;
    __syncthreads();
    sc[tid] += t;
    __syncthreads();
  }
  int loc = sc[tid] - deg;
  if (tid < nd) {
    offs[d0 + tid] = cb + loc;
    dinv[d0 + tid] = rsqrtf((float)deg);
    col[cb + loc] = d0 + tid;     // self-loop first
  }
  scur[tid] = loc + 1;
  __syncthreads();
  for (int j = jb0 + tid; j < jb1; j += 256) {
    unsigned int r = rec[j];
    int p = atomicAdd(&scur[(int)(r & 0xFFFFu)], 1);
    col[cb + p] = (int)(r >> 16);
  }
}

// ---- fused layer0+transform1: T16 = dinv * (relu(x@Win + bin) @ W1) -------
__global__ __launch_bounds__(256) void gemm01_kernel(
    const float* __restrict__ X, const float* __restrict__ Win,
    const float* __restrict__ bin, const float* __restrict__ W1,
    const float* __restrict__ dinv, __half* __restrict__ T16, int n) {
  __shared__ float Ws[64][68];
  __shared__ float Hs[64][68];
  int tid = threadIdx.x;
  int row0 = blockIdx.x * 64;

  for (int i = tid; i < 1024; i += 256) {
    int r = i >> 4, c = (i & 15) << 2;
    *reinterpret_cast<float4*>(&Ws[r][c]) = ((const float4*)Win)[i];
    float4 hv = make_float4(0.f, 0.f, 0.f, 0.f);
    if (row0 + r < n)
      hv = *reinterpret_cast<const float4*>(X + (size_t)(row0 + r) * DD + c);
    *reinterpret_cast<float4*>(&Hs[r][c]) = hv;
  }
  __syncthreads();

  int tr = tid >> 4, tc = tid & 15;
  int r0 = tr << 2, c0 = tc << 2;

  float acc[4][4];
#pragma unroll
  for (int i = 0; i < 4; ++i)
#pragma unroll
    for (int j = 0; j < 4; ++j) acc[i][j] = 0.f;

#pragma unroll
  for (int k = 0; k < 64; ++k) {
    float h0 = Hs[r0 + 0][k], h1 = Hs[r0 + 1][k];
    float h2 = Hs[r0 + 2][k], h3 = Hs[r0 + 3][k];
    float4 wv = *reinterpret_cast<const float4*>(&Ws[k][c0]);
    acc[0][0] = fmaf(h0, wv.x, acc[0][0]); acc[0][1] = fmaf(h0, wv.y, acc[0][1]);
    acc[0][2] = fmaf(h0, wv.z, acc[0][2]); acc[0][3] = fmaf(h0, wv.w, acc[0][3]);
    acc[1][0] = fmaf(h1, wv.x, acc[1][0]); acc[1][1] = fmaf(h1, wv.y, acc[1][1]);
    acc[1][2] = fmaf(h1, wv.z, acc[1][2]); acc[1][3] = fmaf(h1, wv.w, acc[1][3]);
    acc[2][0] = fmaf(h2, wv.x, acc[2][0]); acc[2][1] = fmaf(h2, wv.y, acc[2][1]);
    acc[2][2] = fmaf(h2, wv.z, acc[2][2]); acc[2][3] = fmaf(h2, wv.w, acc[2][3]);
    acc[3][0] = fmaf(h3, wv.x, acc[3][0]); acc[3][1] = fmaf(h3, wv.y, acc[3][1]);
    acc[3][2] = fmaf(h3, wv.z, acc[3][2]); acc[3][3] = fmaf(h3, wv.w, acc[3][3]);
  }

  // h = relu(acc + bin)
  float4 bv = *reinterpret_cast<const float4*>(bin + c0);
#pragma unroll
  for (int i = 0; i < 4; ++i) {
    acc[i][0] = fmaxf(acc[i][0] + bv.x, 0.f);
    acc[i][1] = fmaxf(acc[i][1] + bv.y, 0.f);
    acc[i][2] = fmaxf(acc[i][2] + bv.z, 0.f);
    acc[i][3] = fmaxf(acc[i][3] + bv.w, 0.f);
  }
  __syncthreads();              // everyone done reading Hs/Ws

  // write h tile back into Hs; restage Ws = W1
#pragma unroll
  for (int i = 0; i < 4; ++i)
    *reinterpret_cast<float4*>(&Hs[r0 + i][c0]) =
        make_float4(acc[i][0], acc[i][1], acc[i][2], acc[i][3]);
  for (int i = tid; i < 1024; i += 256) {
    int r = i >> 4, c = (i & 15) << 2;
    *reinterpret_cast<float4*>(&Ws[r][c]) = ((const float4*)W1)[i];
  }
  __syncthreads();

#pragma unroll
  for (int i = 0; i < 4; ++i)
#pragma unroll
    for (int j = 0; j < 4; ++j) acc[i][j] = 0.f;

#pragma unroll
  for (int k = 0; k < 64; ++k) {
    float h0 = Hs[r0 + 0][k], h1 = Hs[r0 + 1][k];
    float h2 = Hs[r0 + 2][k], h3 = Hs[r0 + 3][k];
    float4 wv = *reinterpret_cast<const float4*>(&Ws[k][c0]);
    acc[0][0] = fmaf(h0, wv.x, acc[0][0]); acc[0][1] = fmaf(h0, wv.y, acc[0][1]);
    acc[0][2] = fmaf(h0, wv.z, acc[0][2]); acc[0][3] = fmaf(h0, wv.w, acc[0][3]);
    acc[1][0] = fmaf(h1, wv.x, acc[1][0]); acc[1][1] = fmaf(h1, wv.y, acc[1][1]);
    acc[1][2] = fmaf(h1, wv.z, acc[1][2]); acc[1][3] = fmaf(h1, wv.w, acc[1][3]);
    acc[2][0] = fmaf(h2, wv.x, acc[2][0]); acc[2][1] = fmaf(h2, wv.y, acc[2][1]);
    acc[2][2] = fmaf(h2, wv.z, acc[2][2]); acc[2][3] = fmaf(h2, wv.w, acc[2][3]);
    acc[3][0] = fmaf(h3, wv.x, acc[3][0]); acc[3][1] = fmaf(h3, wv.y, acc[3][1]);
    acc[3][2] = fmaf(h3, wv.z, acc[3][2]); acc[3][3] = fmaf(h3, wv.w, acc[3][3]);
  }

#pragma unroll
  for (int i = 0; i < 4; ++i) {
    long long row = (long long)row0 + r0 + i;
    if (row >= n) break;
    float dv = dinv[row];
    __half2 p01 = __floats2half2_rn(acc[i][0] * dv, acc[i][1] * dv);
    __half2 p23 = __floats2half2_rn(acc[i][2] * dv, acc[i][3] * dv);
    uint2 u;
    u.x = *reinterpret_cast<unsigned int*>(&p01);
    u.y = *reinterpret_cast<unsigned int*>(&p23);
    *reinterpret_cast<uint2*>(T16 + (size_t)row * DD + c0) = u;
  }
}

// ---- dense GEMM: T16 = dinv * (H @ W) -------------------------------------
__global__ __launch_bounds__(256) void gemm_kernel(
    const float* __restrict__ H, const float* __restrict__ W,
    const float* __restrict__ dinv, __half* __restrict__ T16, int n) {
  __shared__ float Ws[64][68];
  __shared__ float Hs[64][68];
  int tid = threadIdx.x;
  int row0 = blockIdx.x * 64;

  for (int i = tid; i < 1024; i += 256) {
    int r = i >> 4, c = (i & 15) << 2;
    *reinterpret_cast<float4*>(&Ws[r][c]) = ((const float4*)W)[i];
    float4 hv = make_float4(0.f, 0.f, 0.f, 0.f);
    if (row0 + r < n)
      hv = *reinterpret_cast<const float4*>(H + (size_t)(row0 + r) * DD + c);
    *reinterpret_cast<float4*>(&Hs[r][c]) = hv;
  }
  __syncthreads();

  int tr = tid >> 4, tc = tid & 15;
  int r0 = tr << 2, c0 = tc << 2;

  float acc[4][4];
#pragma unroll
  for (int i = 0; i < 4; ++i)
#pragma unroll
    for (int j = 0; j < 4; ++j) acc[i][j] = 0.f;

#pragma unroll
  for (int k = 0; k < 64; ++k) {
    float h0 = Hs[r0 + 0][k], h1 = Hs[r0 + 1][k];
    float h2 = Hs[r0 + 2][k], h3 = Hs[r0 + 3][k];
    float4 wv = *reinterpret_cast<const float4*>(&Ws[k][c0]);
    acc[0][0] = fmaf(h0, wv.x, acc[0][0]); acc[0][1] = fmaf(h0, wv.y, acc[0][1]);
    acc[0][2] = fmaf(h0, wv.z, acc[0][2]); acc[0][3] = fmaf(h0, wv.w, acc[0][3]);
    acc[1][0] = fmaf(h1, wv.x, acc[1][0]); acc[1][1] = fmaf(h1, wv.y, acc[1][1]);
    acc[1][2] = fmaf(h1, wv.z, acc[1][2]); acc[1][3] = fmaf(h1, wv.w, acc[1][3]);
    acc[2][0] = fmaf(h2, wv.x, acc[2][0]); acc[2][1] = fmaf(h2, wv.y, acc[2][1]);
    acc[2][2] = fmaf(h2, wv.z, acc[2][2]); acc[2][3] = fmaf(h2, wv.w, acc[2][3]);
    acc[3][0] = fmaf(h3, wv.x, acc[3][0]); acc[3][1] = fmaf(h3, wv.y, acc[3][1]);
    acc[3][2] = fmaf(h3, wv.z, acc[3][2]); acc[3][3] = fmaf(h3, wv.w, acc[3][3]);
  }

#pragma unroll
  for (int i = 0; i < 4; ++i) {
    long long row = (long long)row0 + r0 + i;
    if (row >= n) break;
    float dv = dinv[row];
    __half2 p01 = __floats2half2_rn(acc[i][0] * dv, acc[i][1] * dv);
    __half2 p23 = __floats2half2_rn(acc[i][2] * dv, acc[i][3] * dv);
    uint2 u;
    u.x = *reinterpret_cast<unsigned int*>(&p01);
    u.y = *reinterpret_cast<unsigned int*>(&p23);
    *reinterpret_cast<uint2*>(T16 + (size_t)row * DD + c0) = u;
  }
}

// ---- CSR aggregation: out[d,:] = dinv[d] * sum_{c in N(d)} T16[c,:] + b ---
__device__ __forceinline__ void acc8(float* acc, uint4 u) {
  __half2 h0 = *reinterpret_cast<__half2*>(&u.x);
  __half2 h1 = *reinterpret_cast<__half2*>(&u.y);
  __half2 h2 = *reinterpret_cast<__half2*>(&u.z);
  __half2 h3 = *reinterpret_cast<__half2*>(&u.w);
  float2 f0 = __half22float2(h0);
  float2 f1 = __half22float2(h1);
  float2 f2 = __half22float2(h2);
  float2 f3 = __half22float2(h3);
  acc[0] += f0.x; acc[1] += f0.y;
  acc[2] += f1.x; acc[3] += f1.y;
  acc[4] += f2.x; acc[5] += f2.y;
  acc[6] += f3.x; acc[7] += f3.y;
}

__global__ __launch_bounds__(256) void aggregate_kernel(
    const __half* __restrict__ T, const int* __restrict__ offs,
    const int* __restrict__ col, const float* __restrict__ dinv,
    const float* __restrict__ bias, float* __restrict__ out,
    int n, int relu) {
  int gid = blockIdx.x * blockDim.x + threadIdx.x;
  int wid = gid >> 6;
  if (wid >= n) return;
  int lane = threadIdx.x & 63;
  int g = lane >> 3;
  int s = lane & 7;
  int j0 = offs[wid], j1 = offs[wid + 1];
  int deg = j1 - j0;
  const __half* Ts = T + s * 8;

  float acc[8];
#pragma unroll
  for (int k = 0; k < 8; ++k) acc[k] = 0.f;

  for (int base = 0; base < deg; base += 64) {
    int idx = base + lane;
    int c_local = (idx < deg) ? col[j0 + idx] : -1;
    int rem = deg - base; if (rem > 64) rem = 64;
    int nr = (rem + 7) >> 3;
    int t = 0;
    for (; t + 4 <= nr; t += 4) {
      int i = t * 8 + g;
      int c0 = __shfl(c_local, i, 64);
      int c1 = __shfl(c_local, i + 8, 64);
      int c2 = __shfl(c_local, i + 16, 64);
      int c3 = __shfl(c_local, i + 24, 64);
      uint4 u0 = *reinterpret_cast<const uint4*>(Ts + (size_t)c0 * DD);
      uint4 u1 = *reinterpret_cast<const uint4*>(Ts + (size_t)c1 * DD);
      uint4 u2 = *reinterpret_cast<const uint4*>(Ts + (size_t)c2 * DD);
      if (c3 >= 0) {
        uint4 u3 = *reinterpret_cast<const uint4*>(Ts + (size_t)c3 * DD);
        acc8(acc, u3);
      }
      acc8(acc, u0);
      acc8(acc, u1);
      acc8(acc, u2);
    }
    for (; t < nr; ++t) {
      int i = t * 8 + g;
      int c = __shfl(c_local, i, 64);
      if (c >= 0) {
        uint4 u = *reinterpret_cast<const uint4*>(Ts + (size_t)c * DD);
        acc8(acc, u);
      }
    }
  }

#pragma unroll
  for (int m = 8; m <= 32; m <<= 1) {
#pragma unroll
    for (int k = 0; k < 8; ++k)
      acc[k] += __shfl_xor(acc[k], m, 64);
  }

  if (g == 0) {
    float dv = dinv[wid];
    const float4* bp = reinterpret_cast<const float4*>(bias + s * 8);
    float4 b0 = bp[0], b1 = bp[1];
    float4 o0, o1;
    o0.x = fmaf(acc[0], dv, b0.x);
    o0.y = fmaf(acc[1], dv, b0.y);
    o0.z = fmaf(acc[2], dv, b0.z);
    o0.w = fmaf(acc[3], dv, b0.w);
    o1.x = fmaf(acc[4], dv, b1.x);
    o1.y = fmaf(acc[5], dv, b1.y);
    o1.z = fmaf(acc[6], dv, b1.z);
    o1.w = fmaf(acc[7], dv, b1.w);
    if (relu) {
      o0.x = fmaxf(o0.x, 0.f); o0.y = fmaxf(o0.y, 0.f);
      o0.z = fmaxf(o0.z, 0.f); o0.w = fmaxf(o0.w, 0.f);
      o1.x = fmaxf(o1.x, 0.f); o1.y = fmaxf(o1.y, 0.f);
      o1.z = fmaxf(o1.z, 0.f); o1.w = fmaxf(o1.w, 0.f);
    }
    float4* op = reinterpret_cast<float4*>(out + (size_t)wid * DD + s * 8);
    op[0] = o0;
    op[1] = o1;
  }
}

// ---------------------------------------------------------------------------
extern "C" void kernel_launch(void* const* d_in, const int* in_sizes, int n_in,
                              void* d_out, int out_size, void* d_ws, size_t ws_size,
                              hipStream_t stream) {
  const float* x   = (const float*)d_in[0];
  const void*  eix = d_in[1];
  const float* Win = (const float*)d_in[2];
  const float* bin = (const float*)d_in[3];
  const float* W1  = (const float*)d_in[4];
  const float* b1  = (const float*)d_in[5];
  const float* W2  = (const float*)d_in[6];
  const float* b2  = (const float*)d_in[7];
  const float* W3  = (const float*)d_in[8];
  const float* b3  = (const float*)d_in[9];

  int n = in_sizes[0] / DD;
  int E = in_sizes[1] / 2;
  int M = E + n;
  int chunk = (n + NB - 1) / NB;

  char* w = (char*)d_ws;
  auto carve = [&](size_t bytes) {
    char* p = w;
    w += (bytes + 255) & ~(size_t)255;
    return p;
  };
  int*          ct         = (int*)carve(64);
  int*          histPB     = (int*)carve((size_t)NB * NB * 4);
  int*          localpre   = (int*)carve((size_t)NB * NB * 4);
  int*          tot        = (int*)carve((size_t)NB * 4);
  int*          bucketBase = (int*)carve((size_t)(NB + 1) * 4);
  int*          csrBase    = (int*)carve((size_t)NB * 4);
  int*          offs       = (int*)carve((size_t)(n + 1) * 4);
  float*        dinv       = (float*)carve((size_t)n * 4);
  unsigned int* rec        = (unsigned int*)carve((size_t)E * 4);
  int*          col        = (int*)carve((size_t)M * 4);
  float*        hbuf       = (float*)carve((size_t)n * DD * 4);
  __half*       t16        = (__half*)carve((size_t)n * DD * 2);

  hipMemsetAsync(ct, 0, 64, stream);
  csr_coop_kernel<<<NB, 256, 0, stream>>>(eix, E, n, chunk, histPB, localpre,
                                          tot, bucketBase, csrBase, offs,
                                          dinv, rec, col, ct);

  int gemm_grid = (n + 63) / 64;
  int agg_grid  = (n * 64 + 255) / 256;

  // fused layer0 + conv1 transform: t16 = dinv * (relu(x@Win+bin) @ W1)
  gemm01_kernel<<<gemm_grid, 256, 0, stream>>>(x, Win, bin, W1, dinv, t16, n);
  aggregate_kernel<<<agg_grid, 256, 0, stream>>>(t16, offs, col, dinv, b1, hbuf, n, 1);

  // conv2
  gemm_kernel<<<gemm_grid, 256, 0, stream>>>(hbuf, W2, dinv, t16, n);
  aggregate_kernel<<<agg_grid, 256, 0, stream>>>(t16, offs, col, dinv, b2, hbuf, n, 1);

  // conv3 (no relu)
  gemm_kernel<<<gemm_grid, 256, 0, stream>>>(hbuf, W3, dinv, t16, n);
  aggregate_kernel<<<agg_grid, 256, 0, stream>>>(t16, offs, col, dinv, b3, (float*)d_out, n, 0);
}